// Round 4
// baseline (924905.762 us; speedup 1.0000x reference)
//
#include <hip/hip_runtime.h>

#define AG __HIP_MEMORY_SCOPE_AGENT

// ---------------- device-scope grid barrier (persistent kernels) ----------------
__device__ __forceinline__ void gridbar(int* bar, int nblk) {
  __threadfence();
  __syncthreads();
  if (threadIdx.x == 0) {
    int g = __hip_atomic_load(bar + 1, __ATOMIC_RELAXED, AG);
    int prev = __hip_atomic_fetch_add(bar, 1, __ATOMIC_ACQ_REL, AG);
    if (prev == nblk - 1) {
      __hip_atomic_store(bar, 0, __ATOMIC_RELAXED, AG);
      __hip_atomic_fetch_add(bar + 1, 1, __ATOMIC_ACQ_REL, AG);
    } else {
      while (__hip_atomic_load(bar + 1, __ATOMIC_ACQUIRE, AG) == g)
        __builtin_amdgcn_s_sleep(16);
    }
  }
  __syncthreads();
}

// ---------------- generic f32 GEMM: C = A(MxK) @ B(KxN), optional per-col divide ----------------
__global__ __launch_bounds__(256) void gemm16(const float* __restrict__ A, const float* __restrict__ B,
                                              float* __restrict__ C, int M, int N, int K,
                                              const float* __restrict__ Sdiv) {
  __shared__ float As[16][17], Bs[16][17];
  int tx = threadIdx.x & 15, ty = threadIdx.x >> 4;
  int col = blockIdx.x * 16 + tx, row = blockIdx.y * 16 + ty;
  float acc = 0.f;
  for (int k0 = 0; k0 < K; k0 += 16) {
    As[ty][tx] = A[row * K + k0 + tx];
    Bs[ty][tx] = B[(k0 + ty) * N + col];
    __syncthreads();
#pragma unroll
    for (int kk = 0; kk < 16; ++kk) acc += As[ty][kk] * Bs[kk][tx];
    __syncthreads();
  }
  if (Sdiv) acc /= fmaxf(Sdiv[col], 1e-12f);
  C[row * N + col] = acc;
}

// ---------------- persistent Householder QR (sgeqrf clone, f32 working, fp64 accum); only R kept ----------------
__global__ __launch_bounds__(256) void qr_kernel(float* __restrict__ A, double* __restrict__ red,
                                                 double* __restrict__ red2, double* __restrict__ wv, int* bar) {
  const int tid = threadIdx.x, nb = gridDim.x, bid = blockIdx.x;
  const int g = bid * 256 + tid, NT = nb * 256;
  __shared__ double sred[256];
  const int M = 4096, N = 1024;
  for (int j = 0; j < N; ++j) {
    double p = 0;
    for (int r = j + 1 + g; r < M; r += NT) { double x = (double)A[r * N + j]; p += x * x; }
    sred[tid] = p; __syncthreads();
    for (int off = 128; off > 0; off >>= 1) { if (tid < off) sred[tid] += sred[tid + off]; __syncthreads(); }
    if (tid == 0) red[bid] = sred[0];
    gridbar(bar, nb);
    sred[tid] = (tid < nb) ? red[tid] : 0.0; __syncthreads();
    for (int off = 128; off > 0; off >>= 1) { if (tid < off) sred[tid] += sred[tid + off]; __syncthreads(); }
    double xnorm2 = sred[0];
    double alpha = (double)A[j * N + j];
    double beta, tau, s;
    if (xnorm2 == 0.0) { beta = alpha; tau = 0.0; s = 0.0; }   // dlarfg: H=I
    else {
      beta = -copysign(sqrt(alpha * alpha + xnorm2), alpha);
      tau = (beta - alpha) / beta;
      s = 1.0 / (alpha - beta);
    }
    {
      int cchunk = bid & 15, rchunk = bid >> 4;
      int c = cchunk * 64 + (tid & 63);
      double acc = 0;
      if (c > j && tau != 0.0) {
        for (int r = j + 1 + rchunk * 4 + (tid >> 6); r < M; r += 64)
          acc += (double)A[r * N + j] * (double)A[r * N + c];
      }
      __syncthreads(); sred[tid] = acc; __syncthreads();
      if (tid < 64) {
        double a2 = sred[tid] + sred[tid + 64] + sred[tid + 128] + sred[tid + 192];
        red2[rchunk * 1024 + cchunk * 64 + tid] = a2;
      }
    }
    gridbar(bar, nb);
    if (g < 1024) {
      int c = g;
      if (c > j) {
        double a2 = 0;
        for (int rc = 0; rc < 16; ++rc) a2 += red2[rc * 1024 + c];
        wv[c] = (double)A[j * N + c] + s * a2;
      }
    }
    gridbar(bar, nb);
    if (tau != 0.0) {
      int r = g >> 4, l16 = g & 15;
      if (r >= j) {
        double vr = (r == j) ? 1.0 : s * (double)A[r * N + j];
        double tv = tau * vr;
        for (int c = j + 1 + l16; c < N; c += 16) A[r * N + c] -= (float)(tv * wv[c]);
      }
    }
    if (g == 0) A[j * N + j] = (float)beta;
    gridbar(bar, nb);
  }
}

// ---------------- R (f32 upper) -> fp64 dense, zero lower ----------------
__global__ void copyR(const float* __restrict__ Qw, double* __restrict__ R64) {
  int idx = blockIdx.x * 256 + threadIdx.x;  // 1024^2
  int i = idx >> 10, j = idx & 1023;
  R64[idx] = (j >= i) ? (double)Qw[i * 1024 + j] : 0.0;
}

// ---------------- persistent gebrd (dgebd2 clone, fp64); keeps d,e + RIGHT reflectors (raw) ----------------
__global__ __launch_bounds__(256) void gebrd_kernel(double* __restrict__ A, double* __restrict__ d,
                                                    double* __restrict__ e, double* __restrict__ taup,
                                                    double* __restrict__ svec,
                                                    double* __restrict__ red, double* __restrict__ red2,
                                                    double* __restrict__ wv, int* bar) {
  const int tid = threadIdx.x, nb = gridDim.x, bid = blockIdx.x;
  const int g = bid * 256 + tid, NT = nb * 256;
  __shared__ double sred[256];
  const int n = 1024;
  for (int i = 0; i < n; ++i) {
    // ===== column reflector on A[i..n-1][i] =====
    double p = 0;
    for (int r = i + 1 + g; r < n; r += NT) { double x = A[r * n + i]; p += x * x; }
    sred[tid] = p; __syncthreads();
    for (int off = 128; off > 0; off >>= 1) { if (tid < off) sred[tid] += sred[tid + off]; __syncthreads(); }
    if (tid == 0) red[bid] = sred[0];
    gridbar(bar, nb);
    sred[tid] = (tid < nb) ? red[tid] : 0.0; __syncthreads();
    for (int off = 128; off > 0; off >>= 1) { if (tid < off) sred[tid] += sred[tid + off]; __syncthreads(); }
    double xnorm2 = sred[0];
    double alpha = A[i * n + i];
    double beta, tau, s;
    if (xnorm2 == 0.0) { beta = alpha; tau = 0.0; s = 0.0; }
    else {
      beta = -copysign(sqrt(alpha * alpha + xnorm2), alpha);
      tau = (beta - alpha) / beta;
      s = 1.0 / (alpha - beta);
    }
    {
      int cchunk = bid & 15, rchunk = bid >> 4;
      int c = cchunk * 64 + (tid & 63);
      double acc = 0;
      if (c > i && tau != 0.0) {
        for (int r = i + 1 + rchunk * 4 + (tid >> 6); r < n; r += 64)
          acc += A[r * n + i] * A[r * n + c];
      }
      __syncthreads(); sred[tid] = acc; __syncthreads();
      if (tid < 64) {
        double a2 = sred[tid] + sred[tid + 64] + sred[tid + 128] + sred[tid + 192];
        red2[rchunk * 1024 + cchunk * 64 + tid] = a2;
      }
    }
    gridbar(bar, nb);
    if (g < 1024) {
      int c = g;
      if (c > i) {
        double a2 = 0;
        for (int rc = 0; rc < 16; ++rc) a2 += red2[rc * 1024 + c];
        wv[c] = A[i * n + c] + s * a2;
      }
    }
    gridbar(bar, nb);
    if (tau != 0.0) {
      int r = g >> 4, l16 = g & 15;
      if (r >= i && r < n) {
        double vr = (r == i) ? 1.0 : s * A[r * n + i];
        double tv = tau * vr;
        for (int c = i + 1 + l16; c < n; c += 16) A[r * n + c] -= tv * wv[c];
      }
    }
    if (g == 0) d[i] = beta;
    gridbar(bar, nb);
    // ===== row reflector on A[i][i+1..n-1] =====
    if (i >= n - 1) continue;
    p = 0;
    for (int c = i + 2 + tid; c < n; c += 256) { double x = A[i * n + c]; p += x * x; }
    sred[tid] = p; __syncthreads();
    for (int off = 128; off > 0; off >>= 1) { if (tid < off) sred[tid] += sred[tid + off]; __syncthreads(); }
    double rn2 = sred[0];
    double ralpha = A[i * n + i + 1];
    double rbeta, rtau, rs;
    if (rn2 == 0.0) { rbeta = ralpha; rtau = 0.0; rs = 0.0; }
    else {
      rbeta = -copysign(sqrt(ralpha * ralpha + rn2), ralpha);
      rtau = (rbeta - ralpha) / rbeta;
      rs = 1.0 / (ralpha - rbeta);
    }
    if (rtau != 0.0) {
      int wid = g >> 6, lane = g & 63;
      int r = i + 1 + wid;
      if (r < n) {
        double acc = 0;
        for (int c = i + 2 + lane; c < n; c += 64) acc += A[i * n + c] * A[r * n + c];
        for (int off = 32; off > 0; off >>= 1) acc += __shfl_down(acc, off, 64);
        if (lane == 0) wv[r] = A[r * n + (i + 1)] + rs * acc;
      }
    }
    gridbar(bar, nb);
    if (rtau != 0.0) {
      int r = g >> 4, l16 = g & 15;
      if (r >= i + 1 && r < n) {
        double tw = rtau * wv[r];
        for (int c = i + 1 + l16; c < n; c += 16) {
          double uc = (c == i + 1) ? 1.0 : rs * A[i * n + c];
          A[r * n + c] -= tw * uc;
        }
      }
    }
    if (g == 0) { e[i] = rbeta; taup[i] = rtau; svec[i] = rs; }
    gridbar(bar, nb);
  }
}

// ---------------- leaf: fp64 Jacobi eigen of tridiagonal Gram over cols [lo, lo+n+sq) ----------------
__global__ __launch_bounds__(256) void leafk(const double* __restrict__ dvec, const double* __restrict__ evec,
                                             double* __restrict__ Vout, double* __restrict__ dout,
                                             int lo, int n, int sq) {
  const int M = n + sq, Mp = (M + 1) & ~1;  // pad even (<=34)
  __shared__ double Ta[34 * 34], Tb[34 * 34], Va[34 * 34], Vb[34 * 34];
  __shared__ double al[34], be[34];
  __shared__ int part[34], prm[34];
  int tid = threadIdx.x;
  for (int x = tid; x < Mp * Mp; x += 256) {
    int a = x / Mp, b = x - a * Mp;
    double v = 0;
    if (a < M && b < M) {
      if (a == b) {
        double dd = (a < n) ? dvec[lo + a] : 0.0;
        double ee = (a >= 1) ? evec[lo + a - 1] : 0.0;
        v = dd * dd + ee * ee;
      } else if (b == a + 1 && a < n) v = dvec[lo + a] * evec[lo + a];
      else if (a == b + 1 && b < n) v = dvec[lo + b] * evec[lo + b];
    }
    Ta[x] = v; Va[x] = (a == b) ? 1.0 : 0.0;
  }
  __syncthreads();
  double *T = Ta, *Tn = Tb, *V = Va, *Vn = Vb;
  const int nm1 = Mp - 1, half = Mp / 2;
  for (int r = 0; r < 16 * nm1; ++r) {
    int rr = r % nm1;
    for (int pp = tid; pp < half; pp += 256) {
      int p, q;
      if (pp == 0) { p = nm1; q = rr; }
      else { p = (rr + pp) % nm1; q = (rr - pp + nm1) % nm1; }
      if (p > q) { int t2 = p; p = q; q = t2; }
      double app = T[p * Mp + p], aqq = T[q * Mp + q], apq = T[p * Mp + q];
      double c = 1.0, s = 0.0;
      if (apq != 0.0) {
        double th = (aqq - app) / (2.0 * apq);
        double t2 = 1.0 / (fabs(th) + sqrt(1.0 + th * th));
        if (th < 0.0) t2 = -t2;
        c = 1.0 / sqrt(1.0 + t2 * t2);
        s = t2 * c;
      }
      part[p] = q; part[q] = p;
      al[p] = c; be[p] = -s; al[q] = c; be[q] = s;
    }
    __syncthreads();
    for (int x = tid; x < Mp * Mp; x += 256) {
      int i = x / Mp, j = x - i * Mp;
      int pj = part[j], pi = part[i];
      double aj = al[j], bj = be[j], ai = al[i], bi = be[i];
      Tn[x] = ai * (aj * T[i * Mp + j] + bj * T[i * Mp + pj]) + bi * (aj * T[pi * Mp + j] + bj * T[pi * Mp + pj]);
      Vn[x] = aj * V[i * Mp + j] + bj * V[i * Mp + pj];
    }
    __syncthreads();
    double* t2 = T; T = Tn; Tn = t2;
    t2 = V; V = Vn; Vn = t2;
  }
  if (tid == 0) {
    for (int k = 0; k < M; ++k) prm[k] = k;
    for (int a = 0; a < M; ++a) {
      int best = a;
      for (int b = a + 1; b < M; ++b)
        if (T[prm[b] * Mp + prm[b]] < T[prm[best] * Mp + prm[best]]) best = b;
      int t3 = prm[a]; prm[a] = prm[best]; prm[best] = t3;
    }
    for (int k = 0; k < M; ++k) {
      double lam = T[prm[k] * Mp + prm[k]];
      dout[k] = sqrt(lam > 0.0 ? lam : 0.0);
    }
  }
  __syncthreads();
  for (int x = tid; x < M * M; x += 256) {
    int coord = x / M, j = x - coord * M;
    Vout[coord * M + j] = V[coord * Mp + prm[j]];
  }
}

// ---------------- merge assemble: sort, z, slasd2-clone deflation (z-TOL + Givens; prev=0 enables
//                   the SQRE=1 zero-pair rotation, gap<=TOL only for the null pair) ----------------
__global__ __launch_bounds__(1024) void asmk(const double* __restrict__ Vl, int Ml, const double* __restrict__ dl,
                                             const double* __restrict__ Vr, int Mr, const double* __restrict__ dr,
                                             const double* __restrict__ dvec, const double* __restrict__ evec, int ic,
                                             double* __restrict__ dm, double* __restrict__ z, int* __restrict__ src,
                                             int* __restrict__ defl, int* __restrict__ rlist,
                                             int* __restrict__ rotp, int* __restrict__ rotq,
                                             double* __restrict__ rotc, double* __restrict__ rots,
                                             int* __restrict__ iscr, double* __restrict__ zsum2) {
  const int M = Ml + Mr;
  int t = threadIdx.x;
  __shared__ double alpha_s, beta_s;
  if (t == 0) {
    alpha_s = dvec[ic]; beta_s = evec[ic];
    dm[0] = 0.0; src[0] = 0;                 // left child's null promoted, d forced to exact 0 (slasd2)
    int i = 1, j = 0, k = 1;
    while (k < M) {
      bool takeleft;
      if (i < Ml && j < Mr) takeleft = (dl[i] <= dr[j]);
      else takeleft = (i < Ml);
      if (takeleft) { dm[k] = dl[i]; src[k] = i; ++i; }
      else { dm[k] = dr[j]; src[k] = Ml + j; ++j; }
      ++k;
    }
  }
  __syncthreads();
  for (int k = t; k < M; k += 1024) {
    int s = src[k];
    z[k] = (s < Ml) ? alpha_s * Vl[(Ml - 1) * Ml + s]   // alpha * last coord of left vec
                    : beta_s * Vr[s - Ml];              // beta * first coord of right vec
    defl[k] = 0;
  }
  __syncthreads();
  if (t == 0) {
    const double EPS32 = 5.9604644775390625e-8;   // slamch('E')
    double aa = fabs(alpha_s), bb = fabs(beta_s);
    double tol = aa > bb ? aa : bb;
    if (dm[M - 1] > tol) tol = dm[M - 1];
    tol = 8.0 * EPS32 * tol;
    int prev = 0, nrot = 0;   // prev=0: slot-0 pairable (emulates slasd2's SQRE=1 null rotation)
    for (int J = 1; J < M; ++J) {
      if (fabs(z[J]) <= tol) { defl[J] = 1; z[J] = 0.0; }
      else if (prev >= 0 && (dm[J] - dm[prev]) <= tol) {
        double zp = z[prev], zq = z[J];
        double tau = sqrt(zp * zp + zq * zq);
        double c = zq / tau, s = -zp / tau;            // slasd2: C=Z(J)/TAU, S=-Z(PREV)/TAU
        z[J] = tau; z[prev] = 0.0; defl[prev] = 1;
        rotp[nrot] = prev; rotq[nrot] = J; rotc[nrot] = c; rots[nrot] = s; ++nrot;
        prev = J;
      } else prev = J;
    }
    int K = 0; double s2 = 0;
    for (int J = 0; J < M; ++J) if (!defl[J]) { rlist[K++] = J; s2 += z[J] * z[J]; }
    iscr[0] = K; iscr[1] = nrot; zsum2[0] = s2;
  }
}

// ---------------- secular roots (lambda-space bisection, fp64, strict-interior clamp) ----------------
__global__ __launch_bounds__(256) void seck(const double* __restrict__ dm, const double* __restrict__ z,
                                            const int* __restrict__ iscr, const int* __restrict__ rlist,
                                            const double* __restrict__ zsum2, double* __restrict__ troot, int M) {
  int j = blockIdx.x;
  int K = iscr[0];
  if (j >= K) return;
  __shared__ double sred[256];
  int tid = threadIdx.x;
  double dj = dm[rlist[j]];
  double lo = dj * dj, hi;
  if (j + 1 < K) { double dn = dm[rlist[j + 1]]; hi = dn * dn; }
  else { double dn = dm[rlist[K - 1]]; hi = dn * dn + zsum2[0] * 1.000001 + 1e-290; }
  double lo0 = lo, hi0 = hi;
  for (int it = 0; it < 120; ++it) {
    double mid = 0.5 * (lo + hi);
    if (!(mid > lo && mid < hi)) break;
    double p = 0;
    for (int i = tid; i < M; i += 256) {
      double zi = z[i];
      if (zi != 0.0) { double d2 = dm[i] * dm[i]; p += zi * zi / (d2 - mid); }
    }
    sred[tid] = p; __syncthreads();
    for (int off = 128; off > 0; off >>= 1) { if (tid < off) sred[tid] += sred[tid + off]; __syncthreads(); }
    double f = 1.0 + sred[0];
    __syncthreads();
    if (f < 0.0) lo = mid; else hi = mid;
  }
  if (tid == 0) {
    double tr = 0.5 * (lo + hi);
    if (tr <= lo0) tr = nextafter(lo0, hi0);
    else if (tr >= hi0) tr = nextafter(hi0, lo0);
    troot[j] = tr;
  }
}

// ---------------- merge output order: DLAMRG of secular roots with deflated d's (ascending) ----------------
__global__ void sortoutk(const double* __restrict__ dm, const int* __restrict__ iscr,
                         const double* __restrict__ troot, const int* __restrict__ defl,
                         int* __restrict__ omap, double* __restrict__ dnode, int M) {
  if (threadIdx.x != 0 || blockIdx.x != 0) return;
  int K = iscr[0];
  int r = 0, sidx = 0, out = 0;
  while (out < M) {
    while (sidx < M && !defl[sidx]) ++sidx;
    double dval = (sidx < M) ? dm[sidx] : 1e300;
    double rval = (r < K) ? sqrt(troot[r]) : 1e300;
    if (rval <= dval) { omap[out] = r; dnode[out] = rval; ++r; }
    else { omap[out] = (1 << 20) | sidx; dnode[out] = dval; ++sidx; }
    ++out;
  }
}

// ---------------- coefficient matrix C[i][out] (dlasd3 vector formula + pass-throughs) ----------------
__global__ __launch_bounds__(256) void buildCk(const double* __restrict__ dm, const double* __restrict__ z,
                                               const double* __restrict__ troot, const int* __restrict__ omap,
                                               double* __restrict__ C, int M) {
  int x = blockIdx.x * 256 + threadIdx.x;
  if (x >= M * M) return;
  int i = x / M, out = x - i * M;
  int om = omap[out];
  double v;
  if (om & (1 << 20)) v = ((om & 0xFFFFF) == i) ? 1.0 : 0.0;
  else {
    double zi = z[i];
    if (zi == 0.0) v = 0.0;
    else { double d2 = dm[i] * dm[i]; v = zi / (d2 - troot[om]); }
  }
  C[i * M + out] = v;
}

// ---------------- fold slasd2's Givens rotations into C rows (reverse order back-transform) ----------------
__global__ __launch_bounds__(256) void rotk(double* __restrict__ C, const int* __restrict__ iscr,
                                            const int* __restrict__ rotp, const int* __restrict__ rotq,
                                            const double* __restrict__ rotc, const double* __restrict__ rots, int M) {
  int nrot = iscr[1];
  int tid = threadIdx.x;
  for (int r = nrot - 1; r >= 0; --r) {
    int p = rotp[r], q = rotq[r];
    double c = rotc[r], s = rots[r];
    for (int j = tid; j < M; j += 256) {
      double cp = C[p * M + j], cq = C[q * M + j];
      C[p * M + j] = c * cp - s * cq;
      C[q * M + j] = s * cp + c * cq;
    }
    __syncthreads();
  }
}

// ---------------- normalize C columns to unit 2-norm (slasd3 semantics, positive scale) ----------------
__global__ __launch_bounds__(256) void normk(double* __restrict__ C, int M) {
  int out = blockIdx.x, tid = threadIdx.x;
  __shared__ double sred[256];
  double p = 0;
  for (int i = tid; i < M; i += 256) { double v = C[i * M + out]; p += v * v; }
  sred[tid] = p; __syncthreads();
  for (int off = 128; off > 0; off >>= 1) { if (tid < off) sred[tid] += sred[tid + off]; __syncthreads(); }
  double inv = 1.0 / sqrt(sred[0]);
  __syncthreads();
  for (int i = tid; i < M; i += 256) C[i * M + out] *= inv;
}

// ---------------- V_node = blockdiag(Vl, Vr)[src-permuted] @ C  (fp64 tiled) ----------------
__global__ __launch_bounds__(256) void vmergek(const double* __restrict__ Vl, int Ml,
                                               const double* __restrict__ Vr, int Mr,
                                               const double* __restrict__ C, const int* __restrict__ src,
                                               double* __restrict__ Vout, int M) {
  __shared__ double Bs[16][17], Cs[16][17];
  __shared__ int ss[16];
  int tx = threadIdx.x & 15, ty = threadIdx.x >> 4;
  int r0 = blockIdx.y * 16, o0 = blockIdx.x * 16;
  int row = r0 + ty, out = o0 + tx;
  double acc = 0;
  for (int i0 = 0; i0 < M; i0 += 16) {
    if (threadIdx.x < 16) ss[threadIdx.x] = (i0 + threadIdx.x < M) ? src[i0 + threadIdx.x] : 0;
    __syncthreads();
    int ii = i0 + ty;
    Cs[ty][tx] = (ii < M && out < M) ? C[ii * M + out] : 0.0;
    int s = ss[ty];
    int rr = r0 + tx;
    double b = 0;
    if (ii < M && rr < M) {
      if (s < Ml) { if (rr < Ml) b = Vl[rr * Ml + s]; }
      else { if (rr >= Ml) b = Vr[(rr - Ml) * Mr + (s - Ml)]; }
    }
    Bs[ty][tx] = b;
    __syncthreads();
#pragma unroll
    for (int kk = 0; kk < 16; ++kk) acc += Bs[kk][ty] * Cs[kk][tx];
    __syncthreads();
  }
  if (row < M && out < M) Vout[row * M + out] = acc;
}

// ---------------- gather final V (descending) to f32 + S ----------------
__global__ void gatherVS(const double* __restrict__ Vtop, const double* __restrict__ dtop,
                         float* __restrict__ Vs, float* __restrict__ S) {
  int x = blockIdx.x * 256 + threadIdx.x;  // 1024^2
  int coord = x >> 10, jd = x & 1023;
  Vs[coord * 1024 + jd] = (float)Vtop[coord * 1024 + (1023 - jd)];
  if (x < 1024) S[x] = (float)dtop[1023 - x];
}

// ---------------- apply P1 = G(1)...G(n-2) from the left to VB ----------------
__global__ __launch_bounds__(256) void p1apply(float* __restrict__ VB, const double* __restrict__ A,
                                               const double* __restrict__ taup, const double* __restrict__ svec,
                                               double* __restrict__ red2, double* __restrict__ wv, int* bar) {
  const int tid = threadIdx.x, nb = gridDim.x, bid = blockIdx.x;
  const int g = bid * 256 + tid;
  __shared__ double sred[256];
  const int n = 1024;
  for (int i = n - 3; i >= 0; --i) {
    double rtau = taup[i], rs = svec[i];
    if (rtau == 0.0) continue;
    {
      int jchunk = bid & 15, cchunk = bid >> 4;
      int jj = jchunk * 64 + (tid & 63);
      double acc = 0;
      for (int c = i + 2 + cchunk * 4 + (tid >> 6); c < n; c += 64)
        acc += A[i * n + c] * (double)VB[c * n + jj];
      __syncthreads(); sred[tid] = acc; __syncthreads();
      if (tid < 64) {
        double a2 = sred[tid] + sred[tid + 64] + sred[tid + 128] + sred[tid + 192];
        red2[cchunk * 1024 + jchunk * 64 + tid] = a2;
      }
    }
    gridbar(bar, nb);
    if (g < 1024) {
      int j = g;
      double a2 = 0;
      for (int rc = 0; rc < 16; ++rc) a2 += red2[rc * 1024 + j];
      wv[j] = (double)VB[(i + 1) * n + j] + rs * a2;
    }
    gridbar(bar, nb);
    {
      int r = g >> 6, lane = g & 63;
      if (r >= i + 1 && r < n) {
        double ur = (r == i + 1) ? 1.0 : rs * A[i * n + r];
        double tu = rtau * ur;
        for (int j = lane; j < n; j += 64) VB[r * n + j] -= (float)(tu * wv[j]);
      }
    }
    gridbar(bar, nb);
  }
}

// ---------------- persistent LU with partial pivoting (sgetrf clone, f32) ----------------
__global__ __launch_bounds__(256) void lu_kernel(float* __restrict__ A, int* __restrict__ perm,
                                                 float* __restrict__ redv, int* __restrict__ redi, int* bar) {
  const int tid = threadIdx.x, nb = gridDim.x;
  const int g = blockIdx.x * 256 + tid;
  const int NT = nb * 256;
  __shared__ float sv[256];
  __shared__ int si[256];
  for (int i = g; i < 4096; i += NT) perm[i] = i;
  gridbar(bar, nb);
  for (int k = 0; k < 1024; ++k) {
    float bv = -1.0f; int bi = 0x7fffffff;
    for (int i = k + g; i < 4096; i += NT) {
      float v = fabsf(A[i * 1024 + k]);
      if (v > bv) { bv = v; bi = i; }
    }
    sv[tid] = bv; si[tid] = bi;
    __syncthreads();
    for (int off = 128; off > 0; off >>= 1) {
      if (tid < off) {
        float v2 = sv[tid + off]; int i2 = si[tid + off];
        if (v2 > sv[tid] || (v2 == sv[tid] && i2 < si[tid])) { sv[tid] = v2; si[tid] = i2; }
      }
      __syncthreads();
    }
    if (tid == 0) { redv[blockIdx.x] = sv[0]; redi[blockIdx.x] = si[0]; }
    gridbar(bar, nb);
    sv[tid] = redv[tid]; si[tid] = redi[tid];
    __syncthreads();
    for (int off = 128; off > 0; off >>= 1) {
      if (tid < off) {
        float v2 = sv[tid + off]; int i2 = si[tid + off];
        if (v2 > sv[tid] || (v2 == sv[tid] && i2 < si[tid])) { sv[tid] = v2; si[tid] = i2; }
      }
      __syncthreads();
    }
    int piv = si[0];
    __syncthreads();
    if (blockIdx.x == 0 && tid == 0 && piv != k) { int t2 = perm[k]; perm[k] = perm[piv]; perm[piv] = t2; }
    if (piv != k) {
      for (int j = g; j < 1024; j += NT) {
        float t1 = A[k * 1024 + j], t2 = A[piv * 1024 + j];
        A[k * 1024 + j] = t2; A[piv * 1024 + j] = t1;
      }
    }
    gridbar(bar, nb);
    float rp = 1.0f / A[k * 1024 + k];
    for (int i = k + 1 + g; i < 4096; i += NT) A[i * 1024 + k] *= rp;
    gridbar(bar, nb);
    int tj = g & 1023;
    int j = k + 1 + tj;
    if (j < 1024) {
      float ukj = A[k * 1024 + j];
      for (int i = k + 1 + (g >> 10); i < 4096; i += 64) {
        A[i * 1024 + j] -= A[i * 1024 + k] * ukj;
      }
    }
    gridbar(bar, nb);
  }
}

// ---------------- small helpers ----------------
__global__ void rowsrck(const int* __restrict__ perm, int* __restrict__ rowsrc) {
  int g = blockIdx.x * 256 + threadIdx.x;
  if (g < 4096) rowsrc[perm[g]] = g;
}

__global__ void buildB(const float* __restrict__ Vs, const float* __restrict__ LUf, float* __restrict__ B) {
  int idx = blockIdx.x * 256 + threadIdx.x;
  int i = idx >> 10, j = idx & 1023;
  float uu = (i <= j) ? LUf[i * 1024 + j] : 0.0f;
  float vh = Vs[j * 1024 + i];
  B[idx] = fmaxf(vh, uu);
}

__global__ void buildA(const float* __restrict__ U, const float* __restrict__ LUf, float* __restrict__ A) {
  int idx = blockIdx.x * 256 + threadIdx.x;
  int i = idx >> 10, j = idx & 1023;
  float l = (i > j) ? LUf[i * 1024 + j] : (i == j ? 1.0f : 0.0f);
  A[idx] = 0.5f * (U[idx] + l);
}

__global__ void epilog(float* __restrict__ out, const float* __restrict__ Amat,
                       const float* __restrict__ S, const int* __restrict__ rowsrc) {
  int idx = blockIdx.x * 256 + threadIdx.x;
  int i = idx >> 10, j = idx & 1023;
  out[idx] = out[idx] * S[j] + Amat[rowsrc[i] * 1024 + j];
}

// ---------------- launch ----------------
extern "C" void kernel_launch(void* const* d_in, const int* in_sizes, int n_in,
                              void* d_out, int out_size, void* d_ws, size_t ws_size,
                              hipStream_t stream) {
  const float* x0 = (const float*)d_in[0];
  const float* x1 = (const float*)d_in[1];
  const float* W  = (const float*)d_in[2];
  float* out = (float*)d_out;
  char* ws = (char*)d_ws;

  float*  m     = (float*) (ws + 0);               // 16MB
  double* R64   = (double*)(ws + (16ull << 20));   // 8MB
  double* poolA = (double*)(ws + (24ull << 20));   // 9MB  (levels 0,2,4)
  double* poolB = (double*)(ws + (33ull << 20));   // 5MB  (levels 1,3,5)
  double* Cbuf  = (double*)(ws + (38ull << 20));   // 9MB
  char*   sm    = ws + (47ull << 20);              // 1MB smalls
  float*  U     = (float*) (ws + (48ull << 20));   // 16MB (also QR working copy)
  float*  Qw    = U;
  float*  Am    = (float*) (ws + (64ull << 20));   // 16MB
  float*  Bm    = (float*) (ws + (80ull << 20));   // 4MB
  float*  Vs    = (float*) (ws + (84ull << 20));   // 4MB
  float*  LUf   = (float*) (ws + (88ull << 20));   // 16MB -> end 104MB

  float*  S      = (float*) (sm + 0);
  int*    perm   = (int*)   (sm + (8   << 10));
  int*    rowsrc = (int*)   (sm + (24  << 10));
  double* wv     = (double*)(sm + (40  << 10));
  float*  redv   = (float*) (sm + (48  << 10));
  int*    redi   = (int*)   (sm + (52  << 10));
  int*    bar0   = (int*)   (sm + (56  << 10));
  double* dvec   = (double*)(sm + (60  << 10));
  double* evec   = (double*)(sm + (68  << 10));
  double* taup   = (double*)(sm + (76  << 10));
  double* svec   = (double*)(sm + (84  << 10));
  double* red    = (double*)(sm + (92  << 10));
  double* dpoolA = (double*)(sm + (96  << 10));
  double* dpoolB = (double*)(sm + (112 << 10));
  double* dmS    = (double*)(sm + (128 << 10));
  double* zS     = (double*)(sm + (136 << 10));
  double* trootS = (double*)(sm + (144 << 10));
  double* rotcS  = (double*)(sm + (152 << 10));
  double* rotsS  = (double*)(sm + (160 << 10));
  double* zsum2S = (double*)(sm + (168 << 10));
  int*    iscrS  = (int*)   (sm + (168 << 10) + 128);
  int*    srcS   = (int*)   (sm + (172 << 10));
  int*    deflS  = (int*)   (sm + (176 << 10));
  int*    rlistS = (int*)   (sm + (180 << 10));
  int*    omapS  = (int*)   (sm + (184 << 10));
  int*    rotpS  = (int*)   (sm + (188 << 10));
  int*    rotqS  = (int*)   (sm + (192 << 10));
  double* red2   = (double*)(sm + (256 << 10));    // 128KB
  if (ws_size < (105ull << 20)) return;

  hipMemsetAsync(bar0, 0, 1024, stream);
  dim3 b256(256);

  // m = x0 @ W
  gemm16<<<dim3(64, 256), b256, 0, stream>>>(x0, W, m, 4096, 1024, 1024, nullptr);

  // QR of m (R only, sgeqrf clone); bidiagonalize R (dgebd2 clone)
  hipMemcpyAsync(Qw, m, 4096ull * 1024ull * 4ull, hipMemcpyDeviceToDevice, stream);
  qr_kernel<<<256, 256, 0, stream>>>(Qw, red, red2, wv, bar0);
  copyR<<<4096, 256, 0, stream>>>(Qw, R64);
  gebrd_kernel<<<256, 256, 0, stream>>>(R64, dvec, evec, taup, svec, red, red2, wv, bar0);

  // ---- sbdsdc clone: tree (heap layout, dlasdt-compatible splits) ----
  int t_lo[63], t_n[63], t_sq[63];
  t_lo[0] = 0; t_n[0] = 1024; t_sq[0] = 0;
  for (int i = 0; i < 31; ++i) {
    int lo = t_lo[i], n = t_n[i], sq = t_sq[i], nl = n / 2, nr = n - nl - 1;
    t_lo[2 * i + 1] = lo;          t_n[2 * i + 1] = nl; t_sq[2 * i + 1] = 1;
    t_lo[2 * i + 2] = lo + nl + 1; t_n[2 * i + 2] = nr; t_sq[2 * i + 2] = sq;
  }
  int Voff[63], Doff[63];
  for (int lev = 0; lev <= 5; ++lev) {
    int beg = (1 << lev) - 1, end = (1 << (lev + 1)) - 1, vo = 0, doo = 0;
    for (int i = beg; i < end; ++i) {
      Voff[i] = vo; Doff[i] = doo;
      int Mi = t_n[i] + t_sq[i];
      vo += Mi * Mi; doo += Mi;
    }
  }
  // leaves (level 5 -> poolB)
  for (int i = 31; i < 63; ++i)
    leafk<<<1, 256, 0, stream>>>(dvec, evec, poolB + Voff[i], dpoolB + Doff[i], t_lo[i], t_n[i], t_sq[i]);
  // merges levels 4..0 (odd level -> poolB, even -> poolA)
  for (int lev = 4; lev >= 0; --lev) {
    double* po  = (lev & 1) ? poolB : poolA;
    double* pdo = (lev & 1) ? dpoolB : dpoolA;
    double* pc  = (lev & 1) ? poolA : poolB;   // children pool (lev+1 parity)
    double* pdc = (lev & 1) ? dpoolA : dpoolB;
    int beg = (1 << lev) - 1, end = (1 << (lev + 1)) - 1;
    for (int i = beg; i < end; ++i) {
      int l = 2 * i + 1, r = 2 * i + 2;
      int Ml = t_n[l] + t_sq[l], Mr = t_n[r] + t_sq[r], M = Ml + Mr;
      double *Vl = pc + Voff[l], *Vr = pc + Voff[r];
      double *dl = pdc + Doff[l], *dr = pdc + Doff[r];
      double *Vo = po + Voff[i], *dn = pdo + Doff[i];
      int ic = t_lo[i] + t_n[i] / 2;
      asmk<<<1, 1024, 0, stream>>>(Vl, Ml, dl, Vr, Mr, dr, dvec, evec, ic,
                                   dmS, zS, srcS, deflS, rlistS, rotpS, rotqS, rotcS, rotsS, iscrS, zsum2S);
      seck<<<M, 256, 0, stream>>>(dmS, zS, iscrS, rlistS, zsum2S, trootS, M);
      sortoutk<<<1, 1, 0, stream>>>(dmS, iscrS, trootS, deflS, omapS, dn, M);
      buildCk<<<(M * M + 255) / 256, 256, 0, stream>>>(dmS, zS, trootS, omapS, Cbuf, M);
      rotk<<<1, 256, 0, stream>>>(Cbuf, iscrS, rotpS, rotqS, rotcS, rotsS, M);
      normk<<<M, 256, 0, stream>>>(Cbuf, M);
      vmergek<<<dim3((M + 15) / 16, (M + 15) / 16), b256, 0, stream>>>(Vl, Ml, Vr, Mr, Cbuf, srcS, Vo, M);
    }
  }
  // final V (descending) -> f32; S = sigma descending; then V := P1 * V
  gatherVS<<<4096, 256, 0, stream>>>(poolA + Voff[0], dpoolA + Doff[0], Vs, S);
  p1apply<<<256, 256, 0, stream>>>(Vs, R64, taup, svec, red2, wv, bar0);

  // U = m @ Vs / S  (LAPACK-sign-consistent by construction)
  gemm16<<<dim3(64, 256), b256, 0, stream>>>(m, Vs, U, 4096, 1024, 1024, S);

  // LU of x1 (getrf clone)
  hipMemcpyAsync(LUf, x1, 4096ull * 1024ull * 4ull, hipMemcpyDeviceToDevice, stream);
  lu_kernel<<<256, 256, 0, stream>>>(LUf, perm, redv, redi, bar0);
  rowsrck<<<16, 256, 0, stream>>>(perm, rowsrc);

  // epilogue: b = max(Vh, Uu); a = (U+L)/2; out = (a@b)*S + P@a
  buildB<<<4096, 256, 0, stream>>>(Vs, LUf, Bm);
  buildA<<<16384, 256, 0, stream>>>(U, LUf, Am);
  gemm16<<<dim3(64, 256), b256, 0, stream>>>(Am, Bm, out, 4096, 1024, 1024, nullptr);
  epilog<<<16384, 256, 0, stream>>>(out, Am, S, rowsrc);
}

// Round 5
// 251764.331 us; speedup vs baseline: 3.6737x; 3.6737x over previous
//
#include <hip/hip_runtime.h>

#define AG __HIP_MEMORY_SCOPE_AGENT

// ---------------- device-scope grid barrier ----------------
__device__ __forceinline__ void gridbar(int* bar, int nblk) {
  __threadfence();
  __syncthreads();
  if (threadIdx.x == 0) {
    int g = __hip_atomic_load(bar + 1, __ATOMIC_RELAXED, AG);
    int prev = __hip_atomic_fetch_add(bar, 1, __ATOMIC_ACQ_REL, AG);
    if (prev == nblk - 1) {
      __hip_atomic_store(bar, 0, __ATOMIC_RELAXED, AG);
      __hip_atomic_fetch_add(bar + 1, 1, __ATOMIC_ACQ_REL, AG);
    } else {
      while (__hip_atomic_load(bar + 1, __ATOMIC_ACQUIRE, AG) == g)
        __builtin_amdgcn_s_sleep(16);
    }
  }
  __syncthreads();
}

// ---------------- 64x64 register-tiled f32 GEMM: C = A(MxK)@B(KxN), optional per-col divide ----------------
__global__ __launch_bounds__(256) void gemm64(const float* __restrict__ A, const float* __restrict__ B,
                                              float* __restrict__ C, int M, int N, int K,
                                              const float* __restrict__ Sdiv) {
  __shared__ float As[16][65], Bs[16][65];
  const int tid = threadIdx.x;
  const int n0 = blockIdx.x * 64, m0 = blockIdx.y * 64;
  const int tx = tid & 15, ty = tid >> 4;
  const int lka = tid & 15, lma = tid >> 4;
  const int lnb = tid & 63, lkb = tid >> 6;
  float acc[4][4] = {{0.f}};
  for (int k0 = 0; k0 < K; k0 += 16) {
#pragma unroll
    for (int p = 0; p < 4; ++p)
      As[lka][lma + p * 16] = A[(m0 + lma + p * 16) * K + k0 + lka];
#pragma unroll
    for (int p = 0; p < 4; ++p)
      Bs[lkb + p * 4][lnb] = B[(k0 + lkb + p * 4) * N + n0 + lnb];
    __syncthreads();
#pragma unroll
    for (int kk = 0; kk < 16; ++kk) {
      float a0 = As[kk][ty * 4 + 0], a1 = As[kk][ty * 4 + 1], a2 = As[kk][ty * 4 + 2], a3 = As[kk][ty * 4 + 3];
      float b0 = Bs[kk][tx * 4 + 0], b1 = Bs[kk][tx * 4 + 1], b2 = Bs[kk][tx * 4 + 2], b3 = Bs[kk][tx * 4 + 3];
      acc[0][0] += a0 * b0; acc[0][1] += a0 * b1; acc[0][2] += a0 * b2; acc[0][3] += a0 * b3;
      acc[1][0] += a1 * b0; acc[1][1] += a1 * b1; acc[1][2] += a1 * b2; acc[1][3] += a1 * b3;
      acc[2][0] += a2 * b0; acc[2][1] += a2 * b1; acc[2][2] += a2 * b2; acc[2][3] += a2 * b3;
      acc[3][0] += a3 * b0; acc[3][1] += a3 * b1; acc[3][2] += a3 * b2; acc[3][3] += a3 * b3;
    }
    __syncthreads();
  }
#pragma unroll
  for (int i2 = 0; i2 < 4; ++i2) {
    int row = m0 + ty * 4 + i2;
#pragma unroll
    for (int j2 = 0; j2 < 4; ++j2) {
      int col = n0 + tx * 4 + j2;
      float v = acc[i2][j2];
      if (Sdiv) v /= fmaxf(Sdiv[col], 1e-12f);
      C[row * N + col] = v;
    }
  }
}

// ---------------- persistent QR (sgeqrf clone), column-owner blocks, 1 barrier/col ----------------
__global__ __launch_bounds__(1024) void qr_persist(float* __restrict__ A, int* bar) {
  const int tid = threadIdx.x, bid = blockIdx.x;
  const int co = tid & 15, rc = tid >> 4;
  const int c = bid * 16 + co;
  __shared__ double part[17][64];
  __shared__ double wsh[16];
  const int M = 4096, N = 1024;
  int pendJ = -1; float pendBeta = 0.f;
  for (int j = 0; j < N; ++j) {
    if (pendJ >= 0 && bid == (pendJ >> 4) && tid == 0) A[pendJ * N + pendJ] = pendBeta;
    // partial dots (own cols) + norm (col j), fused single pass
    double acc = 0, accN = 0;
    if (c > j) {
      for (int r = j + 1 + rc; r < M; r += 64) {
        double aj = (double)A[r * N + j];
        acc += aj * (double)A[r * N + c];
        if (co == 0) accN += aj * aj;
      }
    } else if (co == 0) {
      for (int r = j + 1 + rc; r < M; r += 64) { double aj = (double)A[r * N + j]; accN += aj * aj; }
    }
    part[co][rc] = acc;
    if (co == 0) part[16][rc] = accN;
    __syncthreads();
    for (int off = 32; off > 0; off >>= 1) {
      if (rc < off) { part[co][rc] += part[co][rc + off]; if (co == 0) part[16][rc] += part[16][rc + off]; }
      __syncthreads();
    }
    double xnorm2 = part[16][0];
    double alpha = (double)A[j * N + j];
    double beta, tau, s;
    if (xnorm2 == 0.0) { beta = alpha; tau = 0.0; s = 0.0; }
    else {
      beta = -copysign(sqrt(alpha * alpha + xnorm2), alpha);
      tau = (beta - alpha) / beta;
      s = 1.0 / (alpha - beta);
    }
    if (rc == 0 && c > j) wsh[co] = (double)A[j * N + c] + s * part[co][0];
    __syncthreads();
    if (tau != 0.0 && c > j) {
      double tw = tau * wsh[co];
      for (int r = j + rc; r < M; r += 64) {
        double vr = (r == j) ? 1.0 : s * (double)A[r * N + j];
        A[r * N + c] -= (float)(vr * tw);
      }
    }
    pendJ = j; pendBeta = (float)beta;
    gridbar(bar, 64);
  }
  if (bid == ((N - 1) >> 4) && tid == 0) A[(N - 1) * N + (N - 1)] = pendBeta;
}

// ---------------- R (f32 upper) -> fp64 dense, zero lower ----------------
__global__ void copyR(const float* __restrict__ Qw, double* __restrict__ R64) {
  int idx = blockIdx.x * 256 + threadIdx.x;
  int i = idx >> 10, j = idx & 1023;
  R64[idx] = (j >= i) ? (double)Qw[i * 1024 + j] : 0.0;
}

// ---------------- persistent gebrd (dgebd2 clone), owner blocks, 2 barriers/col ----------------
__global__ __launch_bounds__(1024) void gebrd_persist(double* __restrict__ A, double* __restrict__ d,
                                                      double* __restrict__ e, double* __restrict__ taup,
                                                      double* __restrict__ svec, int* bar) {
  const int tid = threadIdx.x, bid = blockIdx.x;
  const int co = tid & 15, rc = tid >> 4;   // column-phase layout (cols fast -> coalesced)
  const int ro = tid >> 6, cc = tid & 63;   // row-phase layout (col idx fast -> coalesced)
  const int c = bid * 16 + co;
  const int rr = bid * 16 + ro;
  __shared__ double part[17][64];
  __shared__ double wsh[16];
  const int n = 1024;
  for (int i = 0; i < n; ++i) {
    // ===== column reflector =====
    double acc = 0, accN = 0;
    if (c > i) {
      for (int r = i + 1 + rc; r < n; r += 64) {
        double ai_ = A[r * n + i];
        acc += ai_ * A[r * n + c];
        if (co == 0) accN += ai_ * ai_;
      }
    } else if (co == 0) {
      for (int r = i + 1 + rc; r < n; r += 64) { double ai_ = A[r * n + i]; accN += ai_ * ai_; }
    }
    part[co][rc] = acc;
    if (co == 0) part[16][rc] = accN;
    __syncthreads();
    for (int off = 32; off > 0; off >>= 1) {
      if (rc < off) { part[co][rc] += part[co][rc + off]; if (co == 0) part[16][rc] += part[16][rc + off]; }
      __syncthreads();
    }
    double xnorm2 = part[16][0];
    double alpha = A[i * n + i];
    double beta, tau, s;
    if (xnorm2 == 0.0) { beta = alpha; tau = 0.0; s = 0.0; }
    else { beta = -copysign(sqrt(alpha * alpha + xnorm2), alpha); tau = (beta - alpha) / beta; s = 1.0 / (alpha - beta); }
    if (rc == 0 && c > i) wsh[co] = A[i * n + c] + s * part[co][0];
    __syncthreads();
    if (tau != 0.0 && c > i) {
      double tw = tau * wsh[co];
      for (int r = i + rc; r < n; r += 64) {
        double vr = (r == i) ? 1.0 : s * A[r * n + i];
        A[r * n + c] -= vr * tw;
      }
    }
    if (bid == 0 && tid == 0) d[i] = beta;
    gridbar(bar, 64);
    if (i >= n - 1) continue;
    // ===== row reflector =====
    acc = 0; accN = 0;
    if (rr > i) {
      for (int ci = i + 2 + cc; ci < n; ci += 64) {
        double av = A[i * n + ci];
        acc += av * A[rr * n + ci];
        if (ro == 0) accN += av * av;
      }
    } else if (ro == 0) {
      for (int ci = i + 2 + cc; ci < n; ci += 64) { double av = A[i * n + ci]; accN += av * av; }
    }
    part[ro][cc] = acc;
    if (ro == 0) part[16][cc] = accN;
    __syncthreads();
    for (int off = 32; off > 0; off >>= 1) {
      if (cc < off) { part[ro][cc] += part[ro][cc + off]; if (ro == 0) part[16][cc] += part[16][cc + off]; }
      __syncthreads();
    }
    double rn2 = part[16][0];
    double ralpha = A[i * n + (i + 1)];
    double rbeta, rtau, rs;
    if (rn2 == 0.0) { rbeta = ralpha; rtau = 0.0; rs = 0.0; }
    else { rbeta = -copysign(sqrt(ralpha * ralpha + rn2), ralpha); rtau = (rbeta - ralpha) / rbeta; rs = 1.0 / (ralpha - rbeta); }
    if (cc == 0 && rr > i) wsh[ro] = A[rr * n + (i + 1)] + rs * part[ro][0];
    __syncthreads();
    if (rtau != 0.0 && rr > i) {
      double tw2 = rtau * wsh[ro];
      for (int ci = i + 1 + cc; ci < n; ci += 64) {
        double uc = (ci == i + 1) ? 1.0 : rs * A[i * n + ci];
        A[rr * n + ci] -= tw2 * uc;
      }
    }
    if (bid == 0 && tid == 0) { e[i] = rbeta; taup[i] = rtau; svec[i] = rs; }
    gridbar(bar, 64);
  }
}

// ---------------- fused leaves: 32 blocks, one leaf each (fp64 Jacobi, as before) ----------------
struct LeafDesc { int lo[32]; int nn[32]; int sq[32]; int voff[32]; int doff[32]; };

__global__ __launch_bounds__(256) void leaves_fused(const double* __restrict__ dvec, const double* __restrict__ evec,
                                                    double* __restrict__ pool, double* __restrict__ dpool, LeafDesc ld) {
  const int li = blockIdx.x;
  const int lo = ld.lo[li], n = ld.nn[li], sq = ld.sq[li];
  double* Vout = pool + ld.voff[li];
  double* dout = dpool + ld.doff[li];
  const int M = n + sq, Mp = (M + 1) & ~1;
  __shared__ double Ta[34 * 34], Tb[34 * 34], Va[34 * 34], Vb[34 * 34];
  __shared__ double al[34], be[34];
  __shared__ int part[34], prm[34];
  int tid = threadIdx.x;
  for (int x = tid; x < Mp * Mp; x += 256) {
    int a = x / Mp, b = x - a * Mp;
    double v = 0;
    if (a < M && b < M) {
      if (a == b) {
        double dd = (a < n) ? dvec[lo + a] : 0.0;
        double ee = (a >= 1) ? evec[lo + a - 1] : 0.0;
        v = dd * dd + ee * ee;
      } else if (b == a + 1 && a < n) v = dvec[lo + a] * evec[lo + a];
      else if (a == b + 1 && b < n) v = dvec[lo + b] * evec[lo + b];
    }
    Ta[x] = v; Va[x] = (a == b) ? 1.0 : 0.0;
  }
  __syncthreads();
  double *T = Ta, *Tn = Tb, *V = Va, *Vn = Vb;
  const int nm1 = Mp - 1, half = Mp / 2;
  for (int r = 0; r < 16 * nm1; ++r) {
    int rr = r % nm1;
    for (int pp = tid; pp < half; pp += 256) {
      int p, q;
      if (pp == 0) { p = nm1; q = rr; }
      else { p = (rr + pp) % nm1; q = (rr - pp + nm1) % nm1; }
      if (p > q) { int t2 = p; p = q; q = t2; }
      double app = T[p * Mp + p], aqq = T[q * Mp + q], apq = T[p * Mp + q];
      double cč = 1.0, sč = 0.0;
      if (apq != 0.0) {
        double th = (aqq - app) / (2.0 * apq);
        double t2 = 1.0 / (fabs(th) + sqrt(1.0 + th * th));
        if (th < 0.0) t2 = -t2;
        cč = 1.0 / sqrt(1.0 + t2 * t2);
        sč = t2 * cč;
      }
      part[p] = q; part[q] = p;
      al[p] = cč; be[p] = -sč; al[q] = cč; be[q] = sč;
    }
    __syncthreads();
    for (int x = tid; x < Mp * Mp; x += 256) {
      int i = x / Mp, j = x - i * Mp;
      int pj = part[j], pi = part[i];
      double aj = al[j], bj = be[j], ai = al[i], bi = be[i];
      Tn[x] = ai * (aj * T[i * Mp + j] + bj * T[i * Mp + pj]) + bi * (aj * T[pi * Mp + j] + bj * T[pi * Mp + pj]);
      Vn[x] = aj * V[i * Mp + j] + bj * V[i * Mp + pj];
    }
    __syncthreads();
    double* t2 = T; T = Tn; Tn = t2;
    t2 = V; V = Vn; Vn = t2;
  }
  if (tid == 0) {
    for (int k = 0; k < M; ++k) prm[k] = k;
    for (int a = 0; a < M; ++a) {
      int best = a;
      for (int b = a + 1; b < M; ++b)
        if (T[prm[b] * Mp + prm[b]] < T[prm[best] * Mp + prm[best]]) best = b;
      int t3 = prm[a]; prm[a] = prm[best]; prm[best] = t3;
    }
    for (int k = 0; k < M; ++k) {
      double lam = T[prm[k] * Mp + prm[k]];
      dout[k] = sqrt(lam > 0.0 ? lam : 0.0);
    }
  }
  __syncthreads();
  for (int x = tid; x < M * M; x += 256) {
    int coord = x / M, j = x - coord * M;
    Vout[coord * M + j] = V[coord * Mp + prm[j]];
  }
}

// ---------------- merge assemble: slasd2-clone deflation (unchanged) ----------------
__global__ __launch_bounds__(1024) void asmk(const double* __restrict__ Vl, int Ml, const double* __restrict__ dl,
                                             const double* __restrict__ Vr, int Mr, const double* __restrict__ dr,
                                             const double* __restrict__ dvec, const double* __restrict__ evec, int ic,
                                             double* __restrict__ dm, double* __restrict__ z, int* __restrict__ src,
                                             int* __restrict__ defl, int* __restrict__ rlist,
                                             int* __restrict__ rotp, int* __restrict__ rotq,
                                             double* __restrict__ rotc, double* __restrict__ rots,
                                             int* __restrict__ iscr, double* __restrict__ zsum2) {
  const int M = Ml + Mr;
  int t = threadIdx.x;
  __shared__ double alpha_s, beta_s;
  if (t == 0) {
    alpha_s = dvec[ic]; beta_s = evec[ic];
    dm[0] = 0.0; src[0] = 0;
    int i = 1, j = 0, k = 1;
    while (k < M) {
      bool takeleft;
      if (i < Ml && j < Mr) takeleft = (dl[i] <= dr[j]);
      else takeleft = (i < Ml);
      if (takeleft) { dm[k] = dl[i]; src[k] = i; ++i; }
      else { dm[k] = dr[j]; src[k] = Ml + j; ++j; }
      ++k;
    }
  }
  __syncthreads();
  for (int k = t; k < M; k += 1024) {
    int s = src[k];
    z[k] = (s < Ml) ? alpha_s * Vl[(Ml - 1) * Ml + s] : beta_s * Vr[s - Ml];
    defl[k] = 0;
  }
  __syncthreads();
  if (t == 0) {
    const double EPS32 = 5.9604644775390625e-8;
    double aa = fabs(alpha_s), bb = fabs(beta_s);
    double tol = aa > bb ? aa : bb;
    if (dm[M - 1] > tol) tol = dm[M - 1];
    tol = 8.0 * EPS32 * tol;
    int prev = 0, nrot = 0;
    for (int J = 1; J < M; ++J) {
      if (fabs(z[J]) <= tol) { defl[J] = 1; z[J] = 0.0; }
      else if (prev >= 0 && (dm[J] - dm[prev]) <= tol) {
        double zp = z[prev], zq = z[J];
        double tau = sqrt(zp * zp + zq * zq);
        double cč = zq / tau, sč = -zp / tau;
        z[J] = tau; z[prev] = 0.0; defl[prev] = 1;
        rotp[nrot] = prev; rotq[nrot] = J; rotc[nrot] = cč; rots[nrot] = sč; ++nrot;
        prev = J;
      } else prev = J;
    }
    int K = 0; double s2 = 0;
    for (int J = 0; J < M; ++J) if (!defl[J]) { rlist[K++] = J; s2 += z[J] * z[J]; }
    iscr[0] = K; iscr[1] = nrot; zsum2[0] = s2;
  }
}

// ---------------- secular roots (unchanged) ----------------
__global__ __launch_bounds__(256) void seck(const double* __restrict__ dm, const double* __restrict__ z,
                                            const int* __restrict__ iscr, const int* __restrict__ rlist,
                                            const double* __restrict__ zsum2, double* __restrict__ troot, int M) {
  int j = blockIdx.x;
  int K = iscr[0];
  if (j >= K) return;
  __shared__ double sred[256];
  int tid = threadIdx.x;
  double dj = dm[rlist[j]];
  double lo = dj * dj, hi;
  if (j + 1 < K) { double dn = dm[rlist[j + 1]]; hi = dn * dn; }
  else { double dn = dm[rlist[K - 1]]; hi = dn * dn + zsum2[0] * 1.000001 + 1e-290; }
  double lo0 = lo, hi0 = hi;
  for (int it = 0; it < 120; ++it) {
    double mid = 0.5 * (lo + hi);
    if (!(mid > lo && mid < hi)) break;
    double p = 0;
    for (int i = tid; i < M; i += 256) {
      double zi = z[i];
      if (zi != 0.0) { double d2 = dm[i] * dm[i]; p += zi * zi / (d2 - mid); }
    }
    sred[tid] = p; __syncthreads();
    for (int off = 128; off > 0; off >>= 1) { if (tid < off) sred[tid] += sred[tid + off]; __syncthreads(); }
    double f = 1.0 + sred[0];
    __syncthreads();
    if (f < 0.0) lo = mid; else hi = mid;
  }
  if (tid == 0) {
    double tr = 0.5 * (lo + hi);
    if (tr <= lo0) tr = nextafter(lo0, hi0);
    else if (tr >= hi0) tr = nextafter(hi0, lo0);
    troot[j] = tr;
  }
}

// ---------------- DLAMRG output order (unchanged) ----------------
__global__ void sortoutk(const double* __restrict__ dm, const int* __restrict__ iscr,
                         const double* __restrict__ troot, const int* __restrict__ defl,
                         int* __restrict__ omap, double* __restrict__ dnode, int M) {
  if (threadIdx.x != 0 || blockIdx.x != 0) return;
  int K = iscr[0];
  int r = 0, sidx = 0, out = 0;
  while (out < M) {
    while (sidx < M && !defl[sidx]) ++sidx;
    double dval = (sidx < M) ? dm[sidx] : 1e300;
    double rval = (r < K) ? sqrt(troot[r]) : 1e300;
    if (rval <= dval) { omap[out] = r; dnode[out] = rval; ++r; }
    else { omap[out] = (1 << 20) | sidx; dnode[out] = dval; ++sidx; }
    ++out;
  }
}

// ---------------- coefficient matrix (unchanged) ----------------
__global__ __launch_bounds__(256) void buildCk(const double* __restrict__ dm, const double* __restrict__ z,
                                               const double* __restrict__ troot, const int* __restrict__ omap,
                                               double* __restrict__ C, int M) {
  int x = blockIdx.x * 256 + threadIdx.x;
  if (x >= M * M) return;
  int i = x / M, out = x - i * M;
  int om = omap[out];
  double v;
  if (om & (1 << 20)) v = ((om & 0xFFFFF) == i) ? 1.0 : 0.0;
  else {
    double zi = z[i];
    if (zi == 0.0) v = 0.0;
    else { double d2 = dm[i] * dm[i]; v = zi / (d2 - troot[om]); }
  }
  C[i * M + out] = v;
}

// ---------------- Givens back-transform (unchanged) ----------------
__global__ __launch_bounds__(256) void rotk(double* __restrict__ C, const int* __restrict__ iscr,
                                            const int* __restrict__ rotp, const int* __restrict__ rotq,
                                            const double* __restrict__ rotc, const double* __restrict__ rots, int M) {
  int nrot = iscr[1];
  int tid = threadIdx.x;
  for (int r = nrot - 1; r >= 0; --r) {
    int p = rotp[r], q = rotq[r];
    double cč = rotc[r], sč = rots[r];
    for (int j = tid; j < M; j += 256) {
      double cp = C[p * M + j], cq = C[q * M + j];
      C[p * M + j] = cč * cp - sč * cq;
      C[q * M + j] = sč * cp + cč * cq;
    }
    __syncthreads();
  }
}

// ---------------- column normalize (unchanged) ----------------
__global__ __launch_bounds__(256) void normk(double* __restrict__ C, int M) {
  int out = blockIdx.x, tid = threadIdx.x;
  __shared__ double sred[256];
  double p = 0;
  for (int i = tid; i < M; i += 256) { double v = C[i * M + out]; p += v * v; }
  sred[tid] = p; __syncthreads();
  for (int off = 128; off > 0; off >>= 1) { if (tid < off) sred[tid] += sred[tid + off]; __syncthreads(); }
  double inv = 1.0 / sqrt(sred[0]);
  __syncthreads();
  for (int i = tid; i < M; i += 256) C[i * M + out] *= inv;
}

// ---------------- V merge GEMM (unchanged) ----------------
__global__ __launch_bounds__(256) void vmergek(const double* __restrict__ Vl, int Ml,
                                               const double* __restrict__ Vr, int Mr,
                                               const double* __restrict__ C, const int* __restrict__ src,
                                               double* __restrict__ Vout, int M) {
  __shared__ double Bs[16][17], Cs[16][17];
  __shared__ int ss[16];
  int tx = threadIdx.x & 15, ty = threadIdx.x >> 4;
  int r0 = blockIdx.y * 16, o0 = blockIdx.x * 16;
  int row = r0 + ty, out = o0 + tx;
  double acc = 0;
  for (int i0 = 0; i0 < M; i0 += 16) {
    if (threadIdx.x < 16) ss[threadIdx.x] = (i0 + threadIdx.x < M) ? src[i0 + threadIdx.x] : 0;
    __syncthreads();
    int ii = i0 + ty;
    Cs[ty][tx] = (ii < M && out < M) ? C[ii * M + out] : 0.0;
    int s = ss[ty];
    int rr = r0 + tx;
    double b = 0;
    if (ii < M && rr < M) {
      if (s < Ml) { if (rr < Ml) b = Vl[rr * Ml + s]; }
      else { if (rr >= Ml) b = Vr[(rr - Ml) * Mr + (s - Ml)]; }
    }
    Bs[ty][tx] = b;
    __syncthreads();
#pragma unroll
    for (int kk = 0; kk < 16; ++kk) acc += Bs[kk][ty] * Cs[kk][tx];
    __syncthreads();
  }
  if (row < M && out < M) Vout[row * M + out] = acc;
}

// ---------------- final V (descending) -> f32 + S ----------------
__global__ void gatherVS(const double* __restrict__ Vtop, const double* __restrict__ dtop,
                         float* __restrict__ Vs, float* __restrict__ S) {
  int x = blockIdx.x * 256 + threadIdx.x;
  int coord = x >> 10, jd = x & 1023;
  Vs[coord * 1024 + jd] = (float)Vtop[coord * 1024 + (1023 - jd)];
  if (x < 1024) S[x] = (float)dtop[1023 - x];
}

// ---------------- apply P1 to Vs: column-independent, NO grid barriers ----------------
__global__ __launch_bounds__(1024) void p1_nobar(float* __restrict__ VB, const double* __restrict__ A,
                                                 const double* __restrict__ taup, const double* __restrict__ svec) {
  const int tid = threadIdx.x, bid = blockIdx.x;
  const int jo = tid & 15, cc = tid >> 4;
  const int j = bid * 16 + jo;
  __shared__ double part[16][64];
  __shared__ double wsh[16];
  const int n = 1024;
  for (int i = n - 3; i >= 0; --i) {
    double rtau = taup[i];
    if (rtau == 0.0) continue;
    double rs = svec[i];
    double acc = 0;
    for (int c2 = i + 2 + cc; c2 < n; c2 += 64) acc += A[i * n + c2] * (double)VB[c2 * n + j];
    part[jo][cc] = acc;
    __syncthreads();
    for (int off = 32; off > 0; off >>= 1) { if (cc < off) part[jo][cc] += part[jo][cc + off]; __syncthreads(); }
    if (cc == 0) wsh[jo] = (double)VB[(i + 1) * n + j] + rs * part[jo][0];
    __syncthreads();
    double tw = rtau * wsh[jo];
    for (int r = i + 1 + cc; r < n; r += 64) {
      double ur = (r == i + 1) ? 1.0 : rs * A[i * n + r];
      VB[r * n + j] -= (float)(tw * ur);
    }
    __syncthreads();
  }
}

// ---------------- persistent LU (sgetrf clone), column-owner blocks, 1 barrier/col ----------------
// Column k's own swap+scale is DEFERRED to step k+1 (LAPACK-order-equivalent); update uses
// raw col-k with piv remap -> bit-identical values to scaled storage.
__global__ __launch_bounds__(1024) void lu_persist(float* __restrict__ A, int* __restrict__ perm, int* bar) {
  const int tid = threadIdx.x, bid = blockIdx.x;
  const int co = tid & 15, rc = tid >> 4;
  const int c0 = bid * 16;
  __shared__ float sv[1024]; __shared__ int si[1024];
  const int M = 4096, N = 1024;
  for (int i2 = bid * 1024 + tid; i2 < M; i2 += 65536) perm[i2] = i2;
  int pendK = -1, pendPiv = -1; float pendRp = 0.f;
  gridbar(bar, 64);
  for (int k = 0; k < N; ++k) {
    // deferred swap+scale of column k-1 by its owner (others only touch cols != k-1 this step)
    if (pendK >= 0 && bid == (pendK >> 4)) {
      if (tid == 0 && pendPiv != pendK) {
        float t = A[pendK * N + pendK];
        A[pendK * N + pendK] = A[pendPiv * N + pendK];
        A[pendPiv * N + pendK] = t;
      }
      __syncthreads();
      for (int r = pendK + 1 + tid; r < M; r += 1024) A[r * N + pendK] *= pendRp;
    }
    // redundant argmax |A[k..M-1][k]|, first-max tiebreak (isamax clone)
    float bv = -1.f; int bi2 = 0x7fffffff;
    for (int r = k + tid; r < M; r += 1024) {
      float v = fabsf(A[r * N + k]);
      if (v > bv) { bv = v; bi2 = r; }
    }
    sv[tid] = bv; si[tid] = bi2;
    __syncthreads();
    for (int off = 512; off > 0; off >>= 1) {
      if (tid < off) {
        float v2 = sv[tid + off]; int j2 = si[tid + off];
        if (v2 > sv[tid] || (v2 == sv[tid] && j2 < si[tid])) { sv[tid] = v2; si[tid] = j2; }
      }
      __syncthreads();
    }
    int piv = si[0];
    float rp = 1.0f / A[piv * N + k];
    // swap rows k<->piv in own columns (except col k: deferred)
    if (piv != k && tid < 16) {
      int c2 = c0 + tid;
      if (c2 != k) { float t = A[k * N + c2]; A[k * N + c2] = A[piv * N + c2]; A[piv * N + c2] = t; }
    }
    if (bid == 0 && tid == 0 && piv != k) { int t2 = perm[k]; perm[k] = perm[piv]; perm[piv] = t2; }
    __syncthreads();
    // rank-1 update of own columns c>k
    {
      int c2 = c0 + co;
      if (c2 > k) {
        float u = A[k * N + c2];
        float Akk = A[k * N + k];
        for (int r = k + 1 + rc; r < M; r += 64) {
          float araw = A[r * N + k];
          float vr = ((r == piv) ? Akk : araw) * rp;
          A[r * N + c2] -= vr * u;
        }
      }
    }
    pendK = k; pendPiv = piv; pendRp = rp;
    gridbar(bar, 64);
  }
  // epilogue: deferred fix for last column
  if (bid == ((N - 1) >> 4)) {
    if (tid == 0 && pendPiv != pendK) {
      float t = A[pendK * N + pendK];
      A[pendK * N + pendK] = A[pendPiv * N + pendK];
      A[pendPiv * N + pendK] = t;
    }
    __syncthreads();
    for (int r = pendK + 1 + tid; r < M; r += 1024) A[r * N + pendK] *= pendRp;
  }
}

// ---------------- small helpers ----------------
__global__ void rowsrck(const int* __restrict__ perm, int* __restrict__ rowsrc) {
  int g = blockIdx.x * 256 + threadIdx.x;
  if (g < 4096) rowsrc[perm[g]] = g;
}

__global__ void buildB(const float* __restrict__ Vs, const float* __restrict__ LUf, float* __restrict__ B) {
  int idx = blockIdx.x * 256 + threadIdx.x;
  int i = idx >> 10, j = idx & 1023;
  float uu = (i <= j) ? LUf[i * 1024 + j] : 0.0f;
  float vh = Vs[j * 1024 + i];
  B[idx] = fmaxf(vh, uu);
}

__global__ void buildA(const float* __restrict__ U, const float* __restrict__ LUf, float* __restrict__ A) {
  int idx = blockIdx.x * 256 + threadIdx.x;
  int i = idx >> 10, j = idx & 1023;
  float l = (i > j) ? LUf[i * 1024 + j] : (i == j ? 1.0f : 0.0f);
  A[idx] = 0.5f * (U[idx] + l);
}

__global__ void epilog(float* __restrict__ out, const float* __restrict__ Amat,
                       const float* __restrict__ S, const int* __restrict__ rowsrc) {
  int idx = blockIdx.x * 256 + threadIdx.x;
  int i = idx >> 10, j = idx & 1023;
  out[idx] = out[idx] * S[j] + Amat[rowsrc[i] * 1024 + j];
}

// ---------------- launch ----------------
extern "C" void kernel_launch(void* const* d_in, const int* in_sizes, int n_in,
                              void* d_out, int out_size, void* d_ws, size_t ws_size,
                              hipStream_t stream) {
  const float* x0 = (const float*)d_in[0];
  const float* x1 = (const float*)d_in[1];
  const float* W  = (const float*)d_in[2];
  float* out = (float*)d_out;
  char* ws = (char*)d_ws;

  float*  m     = (float*) (ws + 0);               // 16MB
  double* R64   = (double*)(ws + (16ull << 20));   // 8MB
  double* poolA = (double*)(ws + (24ull << 20));   // 9MB  (levels 0,2,4)
  double* poolB = (double*)(ws + (33ull << 20));   // 5MB  (levels 1,3,5)
  double* Cbuf  = (double*)(ws + (38ull << 20));   // 9MB
  char*   sm    = ws + (47ull << 20);              // 1MB smalls
  float*  U     = (float*) (ws + (48ull << 20));   // 16MB (also QR working copy)
  float*  Qw    = U;
  float*  Am    = (float*) (ws + (64ull << 20));   // 16MB
  float*  Bm    = (float*) (ws + (80ull << 20));   // 4MB
  float*  Vs    = (float*) (ws + (84ull << 20));   // 4MB
  float*  LUf   = (float*) (ws + (88ull << 20));   // 16MB

  float*  S      = (float*) (sm + 0);
  int*    perm   = (int*)   (sm + (8   << 10));
  int*    rowsrc = (int*)   (sm + (24  << 10));
  int*    bar0   = (int*)   (sm + (56  << 10));
  double* dvec   = (double*)(sm + (60  << 10));
  double* evec   = (double*)(sm + (68  << 10));
  double* taup   = (double*)(sm + (76  << 10));
  double* svec   = (double*)(sm + (84  << 10));
  double* dpoolA = (double*)(sm + (96  << 10));
  double* dpoolB = (double*)(sm + (112 << 10));
  double* dmS    = (double*)(sm + (128 << 10));
  double* zS     = (double*)(sm + (136 << 10));
  double* trootS = (double*)(sm + (144 << 10));
  double* rotcS  = (double*)(sm + (152 << 10));
  double* rotsS  = (double*)(sm + (160 << 10));
  double* zsum2S = (double*)(sm + (168 << 10));
  int*    iscrS  = (int*)   (sm + (168 << 10) + 128);
  int*    srcS   = (int*)   (sm + (172 << 10));
  int*    deflS  = (int*)   (sm + (176 << 10));
  int*    rlistS = (int*)   (sm + (180 << 10));
  int*    omapS  = (int*)   (sm + (184 << 10));
  int*    rotpS  = (int*)   (sm + (188 << 10));
  int*    rotqS  = (int*)   (sm + (192 << 10));
  if (ws_size < (105ull << 20)) return;

  hipMemsetAsync(bar0, 0, 1024, stream);
  dim3 b256(256);

  // m = x0 @ W
  gemm64<<<dim3(16, 64), b256, 0, stream>>>(x0, W, m, 4096, 1024, 1024, nullptr);

  // QR of m (R only); bidiagonalize R
  hipMemcpyAsync(Qw, m, 4096ull * 1024ull * 4ull, hipMemcpyDeviceToDevice, stream);
  qr_persist<<<64, 1024, 0, stream>>>(Qw, bar0);
  copyR<<<4096, 256, 0, stream>>>(Qw, R64);
  gebrd_persist<<<64, 1024, 0, stream>>>(R64, dvec, evec, taup, svec, bar0);

  // ---- sbdsdc clone: tree ----
  int t_lo[63], t_n[63], t_sq[63];
  t_lo[0] = 0; t_n[0] = 1024; t_sq[0] = 0;
  for (int i = 0; i < 31; ++i) {
    int lo = t_lo[i], n = t_n[i], sq = t_sq[i], nl = n / 2, nr = n - nl - 1;
    t_lo[2 * i + 1] = lo;          t_n[2 * i + 1] = nl; t_sq[2 * i + 1] = 1;
    t_lo[2 * i + 2] = lo + nl + 1; t_n[2 * i + 2] = nr; t_sq[2 * i + 2] = sq;
  }
  int Voff[63], Doff[63];
  for (int lev = 0; lev <= 5; ++lev) {
    int beg = (1 << lev) - 1, end = (1 << (lev + 1)) - 1, vo = 0, doo = 0;
    for (int i = beg; i < end; ++i) {
      Voff[i] = vo; Doff[i] = doo;
      int Mi = t_n[i] + t_sq[i];
      vo += Mi * Mi; doo += Mi;
    }
  }
  // leaves (level 5) fused: 32 blocks
  LeafDesc ld;
  for (int i = 0; i < 32; ++i) {
    int nd = 31 + i;
    ld.lo[i] = t_lo[nd]; ld.nn[i] = t_n[nd]; ld.sq[i] = t_sq[nd];
    ld.voff[i] = Voff[nd]; ld.doff[i] = Doff[nd];
  }
  leaves_fused<<<32, 256, 0, stream>>>(dvec, evec, poolB, dpoolB, ld);
  // merges levels 4..0
  for (int lev = 4; lev >= 0; --lev) {
    double* po  = (lev & 1) ? poolB : poolA;
    double* pdo = (lev & 1) ? dpoolB : dpoolA;
    double* pc  = (lev & 1) ? poolA : poolB;
    double* pdc = (lev & 1) ? dpoolA : dpoolB;
    int beg = (1 << lev) - 1, end = (1 << (lev + 1)) - 1;
    for (int i = beg; i < end; ++i) {
      int l = 2 * i + 1, r = 2 * i + 2;
      int Ml = t_n[l] + t_sq[l], Mr = t_n[r] + t_sq[r], M = Ml + Mr;
      double *Vl = pc + Voff[l], *Vr = pc + Voff[r];
      double *dl = pdc + Doff[l], *dr = pdc + Doff[r];
      double *Vo = po + Voff[i], *dn = pdo + Doff[i];
      int ic = t_lo[i] + t_n[i] / 2;
      asmk<<<1, 1024, 0, stream>>>(Vl, Ml, dl, Vr, Mr, dr, dvec, evec, ic,
                                   dmS, zS, srcS, deflS, rlistS, rotpS, rotqS, rotcS, rotsS, iscrS, zsum2S);
      seck<<<M, 256, 0, stream>>>(dmS, zS, iscrS, rlistS, zsum2S, trootS, M);
      sortoutk<<<1, 1, 0, stream>>>(dmS, iscrS, trootS, deflS, omapS, dn, M);
      buildCk<<<(M * M + 255) / 256, 256, 0, stream>>>(dmS, zS, trootS, omapS, Cbuf, M);
      rotk<<<1, 256, 0, stream>>>(Cbuf, iscrS, rotpS, rotqS, rotcS, rotsS, M);
      normk<<<M, 256, 0, stream>>>(Cbuf, M);
      vmergek<<<dim3((M + 15) / 16, (M + 15) / 16), b256, 0, stream>>>(Vl, Ml, Vr, Mr, Cbuf, srcS, Vo, M);
    }
  }
  // final V -> f32 (descending) + S; then V := P1 * V (barrier-free)
  gatherVS<<<4096, 256, 0, stream>>>(poolA + Voff[0], dpoolA + Doff[0], Vs, S);
  p1_nobar<<<64, 1024, 0, stream>>>(Vs, R64, taup, svec);

  // U = m @ Vs / S
  gemm64<<<dim3(16, 64), b256, 0, stream>>>(m, Vs, U, 4096, 1024, 1024, S);

  // LU of x1
  hipMemcpyAsync(LUf, x1, 4096ull * 1024ull * 4ull, hipMemcpyDeviceToDevice, stream);
  lu_persist<<<64, 1024, 0, stream>>>(LUf, perm, bar0);
  rowsrck<<<16, 256, 0, stream>>>(perm, rowsrc);

  // epilogue
  buildB<<<4096, 256, 0, stream>>>(Vs, LUf, Bm);
  buildA<<<16384, 256, 0, stream>>>(U, LUf, Am);
  gemm64<<<dim3(16, 64), b256, 0, stream>>>(Am, Bm, out, 4096, 1024, 1024, nullptr);
  epilog<<<16384, 256, 0, stream>>>(out, Am, S, rowsrc);
}